// Round 25
// baseline (357.855 us; speedup 1.0000x reference)
//
#include <hip/hip_runtime.h>
#include <math.h>

#define NB 32
#define NG 512
#define NC 384
#define NH 768

typedef float f32x4v __attribute__((ext_vector_type(4)));
typedef __bf16 bf16_t;
typedef bf16_t bf16x8 __attribute__((ext_vector_type(8)));
typedef bf16_t bf16x4 __attribute__((ext_vector_type(4)));

__device__ __forceinline__ void split3(float x, bf16_t& h, bf16_t& m, bf16_t& lo)
{
    h = (bf16_t)x;
    float r1 = x - (float)h;
    m = (bf16_t)r1;
    float r2 = r1 - (float)m;
    lo = (bf16_t)r2;
}

// ---------------- Presplit weights into fragment-ordered bf16 planes.
__global__ __launch_bounds__(256) void presplit_W(
    const float* __restrict__ W, bf16_t* __restrict__ planeB, int K, int N)
{
    int tid = blockIdx.x * 256 + threadIdx.x;
    int nkc = K >> 5;
    if (tid >= nkc * N) return;
    int kc = tid / N;
    int col = tid - kc * N;
    bf16x8 rh[4], rm[4], rl[4];
#pragma unroll
    for (int k = 0; k < 32; k++) {
        float x = W[(size_t)(kc * 32 + k) * N + col];
        bf16_t h, m, lo;
        split3(x, h, m, lo);
        const int s = (k >> 2) & 3;
        const int sub = ((k >> 4) << 2) + (k & 3);
        rh[s][sub] = h; rm[s][sub] = m; rl[s][sub] = lo;
    }
    int swz = (col >> 1) & 3;
    size_t b0 = ((size_t)(kc * 3 + 0) * N + col) * 32;
    size_t b1 = ((size_t)(kc * 3 + 1) * N + col) * 32;
    size_t b2 = ((size_t)(kc * 3 + 2) * N + col) * 32;
#pragma unroll
    for (int s = 0; s < 4; s++) {
        int d = (s ^ swz) << 3;
        *(bf16x8*)&planeB[b0 + d] = rh[s];
        *(bf16x8*)&planeB[b1 + d] = rm[s];
        *(bf16x8*)&planeB[b2 + d] = rl[s];
    }
}

// ---------------- GEMM via bf16 MFMA (round-20 structure, launch_bounds 4;
// VGPR 60, no spill. Round-25: bijective XCD swizzle on blockIdx (grids
// 1536/1024 are %8==0) -> contiguous tile chunk per XCD L2, bit-exact).
__global__ __launch_bounds__(256, 4) void gemm_bias_mfma(
    const float* __restrict__ A, const bf16_t* __restrict__ planeB,
    const float* __restrict__ bias, float* __restrict__ Co,
    int M, int N, int K, int mode)
{
    __shared__ __align__(16) bf16_t sA[3][64][32];
    int ntiles = N >> 7;
    int cpx = gridDim.x >> 3;
    int bid = blockIdx.x;
    int wg = (bid & 7) * cpx + (bid >> 3);    // XCD-contiguous tile chunks
    int bm = (wg / ntiles) << 6;
    int bn = (wg % ntiles) << 7;
    int t = threadIdx.x;
    int l = t & 63, w = t >> 6;
    int wr = (w >> 1) << 5;
    int wc = (w & 1) << 6;
    int fr = l & 15;
    int fq = l >> 4;

    int sa_row = t >> 2;
    int sa_k0 = (t & 3) << 3;
    int qA = (sa_k0 >> 2) & 3;
    int hsel = (sa_k0 & 16) ? 4 : 0;
    int aswz = (sa_row >> 1) & 3;
    int colQ0 = ((qA ^ aswz) << 3) + hsel;
    int colQ1 = (((qA + 1) ^ aswz) << 3) + hsel;
    const float* apBase = A + (size_t)(bm + sa_row) * K + sa_k0;

    size_t planeStride = (size_t)N << 5;
    int rb0 = wc + 0 * 16 + fr, rb1 = wc + 1 * 16 + fr;
    int rb2 = wc + 2 * 16 + fr, rb3 = wc + 3 * 16 + fr;
    size_t o0 = ((size_t)(bn + rb0) << 5) + ((fq ^ ((rb0 >> 1) & 3)) << 3);
    size_t o1 = ((size_t)(bn + rb1) << 5) + ((fq ^ ((rb1 >> 1) & 3)) << 3);
    size_t o2 = ((size_t)(bn + rb2) << 5) + ((fq ^ ((rb2 >> 1) & 3)) << 3);
    size_t o3 = ((size_t)(bn + rb3) << 5) + ((fq ^ ((rb3 >> 1) & 3)) << 3);

    f32x4v acc[2][4];
#pragma unroll
    for (int i = 0; i < 2; i++)
#pragma unroll
        for (int j = 0; j < 4; j++) acc[i][j] = (f32x4v)(0.f);

    float4 qa0 = *(const float4*)(apBase);
    float4 qa1 = *(const float4*)(apBase + 4);
    bf16x8 b0H = *(const bf16x8*)&planeB[o0];
    bf16x8 b0M = *(const bf16x8*)&planeB[planeStride + o0];
    bf16x8 b0L = *(const bf16x8*)&planeB[2 * planeStride + o0];
    bf16x8 b1H = *(const bf16x8*)&planeB[o1];
    bf16x8 b1M = *(const bf16x8*)&planeB[planeStride + o1];
    bf16x8 b1L = *(const bf16x8*)&planeB[2 * planeStride + o1];

    int nkc = K >> 5;
    for (int kc = 0; kc < K; kc += 32) {
        int kci = kc >> 5;
        int kciN = (kci + 1 < nkc) ? kci + 1 : kci;
        const bf16_t* pb  = planeB + (size_t)(kci * 3) * planeStride;
        const bf16_t* pbn = planeB + (size_t)(kciN * 3) * planeStride;
        __syncthreads();
        {
            float xs[8] = { qa0.x, qa0.y, qa0.z, qa0.w,
                            qa1.x, qa1.y, qa1.z, qa1.w };
            bf16_t hs[8], ms[8], ls[8];
#pragma unroll
            for (int e = 0; e < 8; e++) split3(xs[e], hs[e], ms[e], ls[e]);
            *(bf16x4*)&sA[0][sa_row][colQ0] = (bf16x4){ hs[0], hs[1], hs[2], hs[3] };
            *(bf16x4*)&sA[0][sa_row][colQ1] = (bf16x4){ hs[4], hs[5], hs[6], hs[7] };
            *(bf16x4*)&sA[1][sa_row][colQ0] = (bf16x4){ ms[0], ms[1], ms[2], ms[3] };
            *(bf16x4*)&sA[1][sa_row][colQ1] = (bf16x4){ ms[4], ms[5], ms[6], ms[7] };
            *(bf16x4*)&sA[2][sa_row][colQ0] = (bf16x4){ ls[0], ls[1], ls[2], ls[3] };
            *(bf16x4*)&sA[2][sa_row][colQ1] = (bf16x4){ ls[4], ls[5], ls[6], ls[7] };
        }
        __syncthreads();
        if (kc + 32 < K) {
            const float* ap = apBase + kc + 32;
            qa0 = *(const float4*)(ap);
            qa1 = *(const float4*)(ap + 4);
        }
        bf16x8 b2H = *(const bf16x8*)&pb[o2];
        bf16x8 b2M = *(const bf16x8*)&pb[planeStride + o2];
        bf16x8 b2L = *(const bf16x8*)&pb[2 * planeStride + o2];
        bf16x8 b3H = *(const bf16x8*)&pb[o3];
        bf16x8 b3M = *(const bf16x8*)&pb[planeStride + o3];
        bf16x8 b3L = *(const bf16x8*)&pb[2 * planeStride + o3];
        bf16x8 afH[2], afM[2], afL[2];
#pragma unroll
        for (int i = 0; i < 2; i++) {
            int ra = wr + i * 16 + fr;
            int pk = (fq ^ ((ra >> 1) & 3)) << 3;
            afH[i] = *(const bf16x8*)&sA[0][ra][pk];
            afM[i] = *(const bf16x8*)&sA[1][ra][pk];
            afL[i] = *(const bf16x8*)&sA[2][ra][pk];
        }
#define MFMA6(i, j, BH, BM, BL)                                               \
        acc[i][j] = __builtin_amdgcn_mfma_f32_16x16x32_bf16(                  \
            afH[i], BH, acc[i][j], 0, 0, 0);                                  \
        acc[i][j] = __builtin_amdgcn_mfma_f32_16x16x32_bf16(                  \
            afH[i], BM, acc[i][j], 0, 0, 0);                                  \
        acc[i][j] = __builtin_amdgcn_mfma_f32_16x16x32_bf16(                  \
            afM[i], BH, acc[i][j], 0, 0, 0);                                  \
        acc[i][j] = __builtin_amdgcn_mfma_f32_16x16x32_bf16(                  \
            afM[i], BM, acc[i][j], 0, 0, 0);                                  \
        acc[i][j] = __builtin_amdgcn_mfma_f32_16x16x32_bf16(                  \
            afH[i], BL, acc[i][j], 0, 0, 0);                                  \
        acc[i][j] = __builtin_amdgcn_mfma_f32_16x16x32_bf16(                  \
            afL[i], BH, acc[i][j], 0, 0, 0);
        MFMA6(0, 0, b0H, b0M, b0L)
        MFMA6(1, 0, b0H, b0M, b0L)
        MFMA6(0, 1, b1H, b1M, b1L)
        MFMA6(1, 1, b1H, b1M, b1L)
        b0H = *(const bf16x8*)&pbn[o0];
        b0M = *(const bf16x8*)&pbn[planeStride + o0];
        b0L = *(const bf16x8*)&pbn[2 * planeStride + o0];
        b1H = *(const bf16x8*)&pbn[o1];
        b1M = *(const bf16x8*)&pbn[planeStride + o1];
        b1L = *(const bf16x8*)&pbn[2 * planeStride + o1];
        MFMA6(0, 2, b2H, b2M, b2L)
        MFMA6(1, 2, b2H, b2M, b2L)
        MFMA6(0, 3, b3H, b3M, b3L)
        MFMA6(1, 3, b3H, b3M, b3L)
#undef MFMA6
    }

    int orow = fq << 2;
#pragma unroll
    for (int j = 0; j < 4; j++) {
        int colg = bn + wc + j * 16 + fr;
        float bj = bias[colg];
#pragma unroll
        for (int i = 0; i < 2; i++) {
            int rowg = bm + wr + i * 16 + orow;
#pragma unroll
            for (int r = 0; r < 4; r++) {
                float val = acc[i][j][r] + bj;
                val = (mode == 0) ? fmaxf(val, 0.f) : val / 0.1f;
                Co[(size_t)(rowg + r) * N + colg] = val;
            }
        }
    }
}

// ======== DPP reduce networks to lane 63 (pure VALU) ========
#define DPP6_MAXF(x)                                                              \
    { int _t;                                                                     \
      _t = __builtin_amdgcn_update_dpp(__float_as_int(x), __float_as_int(x),      \
               0x111, 0xf, 0xf, false); x = fmaxf(x, __int_as_float(_t));         \
      _t = __builtin_amdgcn_update_dpp(__float_as_int(x), __float_as_int(x),      \
               0x112, 0xf, 0xf, false); x = fmaxf(x, __int_as_float(_t));         \
      _t = __builtin_amdgcn_update_dpp(__float_as_int(x), __float_as_int(x),      \
               0x114, 0xf, 0xf, false); x = fmaxf(x, __int_as_float(_t));         \
      _t = __builtin_amdgcn_update_dpp(__float_as_int(x), __float_as_int(x),      \
               0x118, 0xf, 0xf, false); x = fmaxf(x, __int_as_float(_t));         \
      _t = __builtin_amdgcn_update_dpp(__float_as_int(x), __float_as_int(x),      \
               0x142, 0xa, 0xf, false); x = fmaxf(x, __int_as_float(_t));         \
      _t = __builtin_amdgcn_update_dpp(__float_as_int(x), __float_as_int(x),      \
               0x143, 0xc, 0xf, false); x = fmaxf(x, __int_as_float(_t)); }

#define DPP6_ADDF(x)                                                              \
    { int _t;                                                                     \
      _t = __builtin_amdgcn_update_dpp(__float_as_int(x), __float_as_int(x),      \
               0x111, 0xf, 0xf, false); x = x + __int_as_float(_t);               \
      _t = __builtin_amdgcn_update_dpp(__float_as_int(x), __float_as_int(x),      \
               0x112, 0xf, 0xf, false); x = x + __int_as_float(_t);               \
      _t = __builtin_amdgcn_update_dpp(__float_as_int(x), __float_as_int(x),      \
               0x114, 0xf, 0xf, false); x = x + __int_as_float(_t);               \
      _t = __builtin_amdgcn_update_dpp(__float_as_int(x), __float_as_int(x),      \
               0x118, 0xf, 0xf, false); x = x + __int_as_float(_t);               \
      _t = __builtin_amdgcn_update_dpp(__float_as_int(x), __float_as_int(x),      \
               0x142, 0xa, 0xf, false); x = x + __int_as_float(_t);               \
      _t = __builtin_amdgcn_update_dpp(__float_as_int(x), __float_as_int(x),      \
               0x143, 0xc, 0xf, false); x = x + __int_as_float(_t); }

// ---------------- Fused Sinkhorn iteration. Round-25: grid NB*16, 512 thr /
// 8 waves (4 rows/wave, 32 rows/block) -> 2 blocks/CU x 8 waves = 16
// waves/CU (TLP was the binder). ps partials regroup 8x64 -> 16x32 rows
// (same 512 terms/col, different association -- class validated in r24).
// u (row LSE) stays bit-identical. 2-deep row prefetch kept.
__global__ __launch_bounds__(512) void sinkhorn_iter_fused(
    const float* __restrict__ A0, float* __restrict__ uu,
    const float* __restrict__ vIn, float* __restrict__ vOut,
    const float* __restrict__ psIn, float* __restrict__ psOut, int first)
{
    int blk = blockIdx.x;          // NB*16
    int b = blk >> 4, rc = blk & 15;
    int t = threadIdx.x;           // 0..511
    int l = t & 63, w = t >> 6;    // 8 waves
    __shared__ __align__(16) float svv[512];

    if (first) {
        svv[t] = 0.f;
    } else {
        float S = 0.f;
#pragma unroll
        for (int r16 = 0; r16 < 16; r16++) S += psIn[((b << 4) + r16) * NG + t];
        float nv = vIn[(b << 9) + t] - __logf(S);
        svv[t] = nv;
        if (rc == 0) vOut[(b << 9) + t] = nv;
    }
    __syncthreads();

    float4 v0 = *(const float4*)(&svv[4 * l]);
    float4 v1 = *(const float4*)(&svv[256 + 4 * l]);
    int row0 = (rc << 5) + (w << 2);        // 4 rows per wave
    const float* base = A0 + ((size_t)((b << 9) + row0) << 9);

    float cs0 = 0.f, cs1 = 0.f, cs2 = 0.f, cs3 = 0.f;
    float cs4 = 0.f, cs5 = 0.f, cs6 = 0.f, cs7 = 0.f;

    // 3-stage pipeline: a = row rr, b = rr+1, c = rr+2 in flight
    float4 a0 = *(const float4*)(base + 4 * l);
    float4 a1 = *(const float4*)(base + 256 + 4 * l);
    float4 b0 = *(const float4*)(base + (1 << 9) + 4 * l);
    float4 b1 = *(const float4*)(base + (1 << 9) + 256 + 4 * l);

#pragma unroll
    for (int rr = 0; rr < 4; ++rr) {
        float4 c0, c1;
        if (rr < 2) {
            const float* nrow = base + ((size_t)(rr + 2) << 9);
            c0 = *(const float4*)(nrow + 4 * l);
            c1 = *(const float4*)(nrow + 256 + 4 * l);
        }
        float x0 = a0.x + v0.x, x1 = a0.y + v0.y;
        float x2 = a0.z + v0.z, x3 = a0.w + v0.w;
        float x4 = a1.x + v1.x, x5 = a1.y + v1.y;
        float x6 = a1.z + v1.z, x7 = a1.w + v1.w;
        float m = fmaxf(fmaxf(fmaxf(x0, x1), fmaxf(x2, x3)),
                        fmaxf(fmaxf(x4, x5), fmaxf(x6, x7)));
        DPP6_MAXF(m)
        int mi = __builtin_amdgcn_readlane(__float_as_int(m), 63);
        m = __int_as_float(mi);
        float e0 = __expf(x0 - m), e1 = __expf(x1 - m);
        float e2 = __expf(x2 - m), e3 = __expf(x3 - m);
        float e4 = __expf(x4 - m), e5 = __expf(x5 - m);
        float e6 = __expf(x6 - m), e7 = __expf(x7 - m);
        float s = ((e0 + e1) + (e2 + e3)) + ((e4 + e5) + (e6 + e7));
        DPP6_ADDF(s)
        int si = __builtin_amdgcn_readlane(__float_as_int(s), 63);
        s = __int_as_float(si);
        float inv = 1.0f / s;
        cs0 += e0 * inv; cs1 += e1 * inv; cs2 += e2 * inv; cs3 += e3 * inv;
        cs4 += e4 * inv; cs5 += e5 * inv; cs6 += e6 * inv; cs7 += e7 * inv;
        if (l == 63) uu[(b << 9) + row0 + rr] = -(m + __logf(s));
        a0 = b0; a1 = b1;
        b0 = c0; b1 = c1;
    }

    __shared__ float sacc[8][512];
    float4 w0; w0.x = cs0; w0.y = cs1; w0.z = cs2; w0.w = cs3;
    float4 w1; w1.x = cs4; w1.y = cs5; w1.z = cs6; w1.w = cs7;
    *(float4*)&sacc[w][4 * l] = w0;
    *(float4*)&sacc[w][256 + 4 * l] = w1;
    __syncthreads();
    float pA = sacc[0][t] + sacc[1][t] + sacc[2][t] + sacc[3][t]
             + sacc[4][t] + sacc[5][t] + sacc[6][t] + sacc[7][t];
    int o = ((b << 4) + rc) * NG;
    psOut[o + t] = pA;
}

// ---------------- final combine: vOut = vIn - log(colsum(psIn))
__global__ __launch_bounds__(256) void col_combine_final(
    const float* __restrict__ psIn, const float* __restrict__ vIn,
    float* __restrict__ vOut)
{
    int tid = blockIdx.x * 256 + threadIdx.x;  // NB*NG
    int b = tid >> 9, j = tid & 511;
    float S = 0.f;
#pragma unroll
    for (int r16 = 0; r16 < 16; r16++) S += psIn[((b << 4) + r16) * NG + j];
    vOut[tid] = vIn[tid] - __logf(S);
}

// wave-cooperative masked row argmax over cols 8l..8l+7 per lane.
__device__ __forceinline__ void masked_row_argmax(
    const float* __restrict__ rowp, int l, unsigned int free8, int rr,
    float& outV, int& outF)
{
    float4 x0 = *(const float4*)(rowp + 8 * l);
    float4 x1 = *(const float4*)(rowp + 8 * l + 4);
    float q0 = (free8 & 1u)   ? x0.x : -1.0f;
    float q1 = (free8 & 2u)   ? x0.y : -1.0f;
    float q2 = (free8 & 4u)   ? x0.z : -1.0f;
    float q3 = (free8 & 8u)   ? x0.w : -1.0f;
    float q4 = (free8 & 16u)  ? x1.x : -1.0f;
    float q5 = (free8 & 32u)  ? x1.y : -1.0f;
    float q6 = (free8 & 64u)  ? x1.z : -1.0f;
    float q7 = (free8 & 128u) ? x1.w : -1.0f;
    float lm = fmaxf(fmaxf(fmaxf(q0, q1), fmaxf(q2, q3)),
                     fmaxf(fmaxf(q4, q5), fmaxf(q6, q7)));
    int sb = (rr << 9) + 8 * l;
    int lf = 0x7FFFFFFF;
    lf = (q7 == lm) ? sb + 7 : lf;
    lf = (q6 == lm) ? sb + 6 : lf;
    lf = (q5 == lm) ? sb + 5 : lf;
    lf = (q4 == lm) ? sb + 4 : lf;
    lf = (q3 == lm) ? sb + 3 : lf;
    lf = (q2 == lm) ? sb + 2 : lf;
    lf = (q1 == lm) ? sb + 1 : lf;
    lf = (q0 == lm) ? sb + 0 : lf;
    float gg = lm;
    DPP6_MAXF(gg)
    int ggi = __builtin_amdgcn_readlane(__float_as_int(gg), 63);
    float g1 = __int_as_float(ggi);
    unsigned long long tb = __ballot(lm == g1);
    int tl = __ffsll(tb) - 1;
    outV = g1;
    outF = __builtin_amdgcn_readlane(lf, tl);
}

// ---------------- P = exp((A0+u)+v) (libm expf) + per-row argmax + state init.
__global__ __launch_bounds__(256) void p_rowmax(
    const float* __restrict__ A0, const float* __restrict__ uu,
    const float* __restrict__ vv, float* __restrict__ P,
    int* __restrict__ rbCr, int* __restrict__ rbCc,
    unsigned long long* __restrict__ freeRow,
    unsigned long long* __restrict__ freeCol,
    int* __restrict__ remaining)
{
    if (blockIdx.x == 0) {
        int t = threadIdx.x;
        freeRow[t] = ~0ULL;
        freeCol[t] = ~0ULL;
        if (t < NB) remaining[t] = NG;
    }
    int wrow = blockIdx.x * 4 + (threadIdx.x >> 6);
    int l = threadIdx.x & 63;
    int b = wrow >> 9;
    float ur = uu[wrow];
    const float* vb = vv + (b << 9);
    size_t ro = (size_t)wrow << 9;
    float4 a0 = *(const float4*)(A0 + ro + 8 * l);
    float4 a1 = *(const float4*)(A0 + ro + 8 * l + 4);
    float4 v0 = *(const float4*)(vb + 8 * l);
    float4 v1 = *(const float4*)(vb + 8 * l + 4);
    float p0 = expf(a0.x + ur + v0.x);
    float p1 = expf(a0.y + ur + v0.y);
    float p2 = expf(a0.z + ur + v0.z);
    float p3 = expf(a0.w + ur + v0.w);
    float p4 = expf(a1.x + ur + v1.x);
    float p5 = expf(a1.y + ur + v1.y);
    float p6 = expf(a1.z + ur + v1.z);
    float p7 = expf(a1.w + ur + v1.w);
    float4 o0; o0.x = p0; o0.y = p1; o0.z = p2; o0.w = p3;
    float4 o1; o1.x = p4; o1.y = p5; o1.z = p6; o1.w = p7;
    *(float4*)(P + ro + 8 * l) = o0;
    *(float4*)(P + ro + 8 * l + 4) = o1;
    float mv = fmaxf(fmaxf(fmaxf(p0, p1), fmaxf(p2, p3)),
                     fmaxf(fmaxf(p4, p5), fmaxf(p6, p7)));
    int cb = 8 * l;
    int f = 0x7FFFFFFF;
    f = (p7 == mv) ? cb + 7 : f;
    f = (p6 == mv) ? cb + 6 : f;
    f = (p5 == mv) ? cb + 5 : f;
    f = (p4 == mv) ? cb + 4 : f;
    f = (p3 == mv) ? cb + 3 : f;
    f = (p2 == mv) ? cb + 2 : f;
    f = (p1 == mv) ? cb + 1 : f;
    f = (p0 == mv) ? cb + 0 : f;
    float g = mv;
    DPP6_MAXF(g)
    int gi = __builtin_amdgcn_readlane(__float_as_int(g), 63);
    float gm = __int_as_float(gi);
    unsigned long long tb = __ballot(mv == gm);
    int tl = __ffsll(tb) - 1;
    int bestc = __builtin_amdgcn_readlane(f, tl);
    if (l == 0) { rbCr[wrow] = bestc; rbCc[wrow] = -1; }
}

// ---------------- One parallel mutual-max round (exact greedy equivalence).
__global__ __launch_bounds__(512) void mutual_round(
    const float* __restrict__ P, int* __restrict__ rbCr, int* __restrict__ rbCc,
    unsigned long long* __restrict__ freeRow,
    unsigned long long* __restrict__ freeCol,
    int* __restrict__ remaining, int* __restrict__ permInt)
{
    int b = blockIdx.x;
    if (remaining[b] == 0) return;
    int t = threadIdx.x;
    int l = t & 63;
    int w = t >> 6;
    const float* Pb = P + (size_t)b * NG * NG;

    __shared__ unsigned int fr[16], fc[16];
    __shared__ int sRC[NG];
    __shared__ int sCC[NG];
    __shared__ int freeList[NG];
    __shared__ int dirtyRows[NG];
    __shared__ int nFree, nDirtyRow, takeCnt;
    __shared__ int wCnt[8], wOff[8];

    if (t < 8) {
        unsigned long long x = freeRow[b * 8 + t];
        fr[2 * t] = (unsigned)x; fr[2 * t + 1] = (unsigned)(x >> 32);
    } else if (t < 16) {
        int i = t - 8;
        unsigned long long x = freeCol[b * 8 + i];
        fc[2 * i] = (unsigned)x; fc[2 * i + 1] = (unsigned)(x >> 32);
    }
    sRC[t] = rbCr[(b << 9) + t];
    sCC[t] = rbCc[(b << 9) + t];
    if (t == 0) { nDirtyRow = 0; takeCnt = 0; }
    __syncthreads();

    bool isFree = (fr[t >> 5] >> (t & 31)) & 1u;
    unsigned long long bm = __ballot(isFree);
    if (l == 0) wCnt[w] = __popcll(bm);
    if (isFree) {
        int c = sRC[t];
        if (!((fc[c >> 5] >> (c & 31)) & 1u)) {
            int d = atomicAdd(&nDirtyRow, 1);
            dirtyRows[d] = t;
        }
    }
    __syncthreads();
    if (t == 0) {
        int s = 0;
#pragma unroll
        for (int i = 0; i < 8; i++) { wOff[i] = s; s += wCnt[i]; }
        nFree = s;
    }
    __syncthreads();
    if (isFree) {
        int rank = __popcll(bm & ((1ULL << l) - 1ULL));
        freeList[wOff[w] + rank] = t;
    }
    __syncthreads();

    int nd = nDirtyRow;
    for (int d = w; d < nd; d += 8) {
        int r = dirtyRows[d];
        unsigned int free8 = (fc[l >> 2] >> ((l & 3) * 8)) & 0xFFu;
        float nv; int nf;
        masked_row_argmax(Pb + ((size_t)r << 9), l, free8, r, nv, nf);
        if (l == 0) {
            int c = nf & 511;
            sRC[r] = c;
            rbCr[(b << 9) + r] = c;
        }
    }
    __syncthreads();

    bool colFree = (fc[t >> 5] >> (t & 31)) & 1u;
    int cachedR = sCC[t];
    bool colDirty = colFree &&
        (cachedR < 0 || !((fr[cachedR >> 5] >> (cachedR & 31)) & 1u));
    if (colDirty) {
        float best = -1.f; int bestr = 0x7FFFFFFF;
        int nf2 = nFree;
        int i = 0;
        for (; i + 4 <= nf2; i += 4) {
            int r0 = freeList[i], r1 = freeList[i + 1];
            int r2 = freeList[i + 2], r3 = freeList[i + 3];
            float v0 = Pb[((size_t)r0 << 9) + t];
            float v1 = Pb[((size_t)r1 << 9) + t];
            float v2 = Pb[((size_t)r2 << 9) + t];
            float v3 = Pb[((size_t)r3 << 9) + t];
            if (v0 > best) { best = v0; bestr = r0; }
            if (v1 > best) { best = v1; bestr = r1; }
            if (v2 > best) { best = v2; bestr = r2; }
            if (v3 > best) { best = v3; bestr = r3; }
        }
        for (; i < nf2; ++i) {
            int ri = freeList[i];
            float vv2 = Pb[((size_t)ri << 9) + t];
            if (vv2 > best) { best = vv2; bestr = ri; }
        }
        sCC[t] = bestr;
        rbCc[(b << 9) + t] = bestr;
    }
    __syncthreads();

    if (colFree) {
        int r = sCC[t];
        if (r >= 0 && r < NG && sRC[r] == t) {
            permInt[(b << 9) + r] = t;
            atomicAnd(&fr[r >> 5], ~(1u << (r & 31)));
            atomicAnd(&fc[t >> 5], ~(1u << (t & 31)));
            atomicAdd(&takeCnt, 1);
        }
    }
    __syncthreads();
    if (t < 8) {
        freeRow[b * 8 + t] =
            ((unsigned long long)fr[2 * t + 1] << 32) | fr[2 * t];
    } else if (t < 16) {
        int i = t - 8;
        freeCol[b * 8 + i] =
            ((unsigned long long)fc[2 * i + 1] << 32) | fc[2 * i];
    }
    if (t == 0) remaining[b] = remaining[b] - takeCnt;
}

// ---------------- Exact sequential cleanup (rarely does work).
__global__ __launch_bounds__(64) void greedy_cleanup(
    const float* __restrict__ P,
    const unsigned long long* __restrict__ freeRow,
    const unsigned long long* __restrict__ freeCol,
    const int* __restrict__ remaining, int* __restrict__ permInt)
{
    int b = blockIdx.x;
    if (remaining[b] == 0) return;
    int l = threadIdx.x;
    const float* Pb = P + (size_t)b * NG * NG;

    unsigned long long wR = freeRow[b * 8 + (l >> 3)];
    unsigned int myRows = (unsigned int)((wR >> ((l & 7) * 8)) & 0xFF);
    unsigned long long wC = freeCol[b * 8 + (l >> 3)];
    unsigned int free8 = (unsigned int)((wC >> ((l & 7) * 8)) & 0xFF);

    float rv[8]; int rf[8];
#pragma unroll
    for (int k = 0; k < 8; k++) { rv[k] = -1.f; rf[k] = 0x7FFFFFFF; }

    int dmk = (int)myRows;
    unsigned long long act = __ballot(dmk != 0);
    while (act) {
        int src = __ffsll(act) - 1;
        int kk = __ffs(__builtin_amdgcn_readlane(dmk, src)) - 1;
        if (l == src) dmk &= ~(1 << kk);
        int rr = (src << 3) + kk;
        float nv; int nf;
        masked_row_argmax(Pb + ((size_t)rr << 9), l, free8, rr, nv, nf);
        bool upd = (l == src);
        rv[0] = (upd && kk == 0) ? nv : rv[0]; rf[0] = (upd && kk == 0) ? nf : rf[0];
        rv[1] = (upd && kk == 1) ? nv : rv[1]; rf[1] = (upd && kk == 1) ? nf : rf[1];
        rv[2] = (upd && kk == 2) ? nv : rv[2]; rf[2] = (upd && kk == 2) ? nf : rf[2];
        rv[3] = (upd && kk == 3) ? nv : rv[3]; rf[3] = (upd && kk == 3) ? nf : rf[3];
        rv[4] = (upd && kk == 4) ? nv : rv[4]; rf[4] = (upd && kk == 4) ? nf : rf[4];
        rv[5] = (upd && kk == 5) ? nv : rv[5]; rf[5] = (upd && kk == 5) ? nf : rf[5];
        rv[6] = (upd && kk == 6) ? nv : rv[6]; rf[6] = (upd && kk == 6) ? nf : rf[6];
        rv[7] = (upd && kk == 7) ? nv : rv[7]; rf[7] = (upd && kk == 7) ? nf : rf[7];
        act = __ballot(dmk != 0);
    }

    for (int step = 0; step < NG; ++step) {
        float mv = fmaxf(fmaxf(fmaxf(rv[0], rv[1]), fmaxf(rv[2], rv[3])),
                         fmaxf(fmaxf(rv[4], rv[5]), fmaxf(rv[6], rv[7])));
        int f = 0x7FFFFFFF;
        f = (rv[7] == mv) ? rf[7] : f;
        f = (rv[6] == mv) ? rf[6] : f;
        f = (rv[5] == mv) ? rf[5] : f;
        f = (rv[4] == mv) ? rf[4] : f;
        f = (rv[3] == mv) ? rf[3] : f;
        f = (rv[2] == mv) ? rf[2] : f;
        f = (rv[1] == mv) ? rf[1] : f;
        f = (rv[0] == mv) ? rf[0] : f;
        float g = mv;
        DPP6_MAXF(g)
        int gi = __builtin_amdgcn_readlane(__float_as_int(g), 63);
        float gm = __int_as_float(gi);
        if (gm < 0.f) break;
        unsigned long long tb = __ballot(mv == gm);
        int tl = __ffsll(tb) - 1;
        int bestf = __builtin_amdgcn_readlane(f, tl);
        int r = bestf >> 9, c = bestf & 511;
        if (l == 0) permInt[(b << 9) + r] = c;
        if (l == (c >> 3)) free8 &= ~(1u << (c & 7));
        int rl = r - (l << 3);
        int dm2 = 0;
#pragma unroll
        for (int k = 0; k < 8; k++) {
            bool alive = rv[k] >= 0.f;
            bool cm = ((rf[k] ^ c) & 511) == 0;
            bool taken = (rl == k);
            if (taken) rv[k] = -1.f;
            dm2 |= (alive && cm && !taken) ? (1 << k) : 0;
        }
        unsigned long long act2 = __ballot(dm2 != 0);
        while (act2) {
            int src = __ffsll(act2) - 1;
            int kk = __ffs(__builtin_amdgcn_readlane(dm2, src)) - 1;
            if (l == src) dm2 &= ~(1 << kk);
            int rr = (src << 3) + kk;
            float nv; int nf;
            masked_row_argmax(Pb + ((size_t)rr << 9), l, free8, rr, nv, nf);
            bool upd = (l == src);
            rv[0] = (upd && kk == 0) ? nv : rv[0]; rf[0] = (upd && kk == 0) ? nf : rf[0];
            rv[1] = (upd && kk == 1) ? nv : rv[1]; rf[1] = (upd && kk == 1) ? nf : rf[1];
            rv[2] = (upd && kk == 2) ? nv : rv[2]; rf[2] = (upd && kk == 2) ? nf : rf[2];
            rv[3] = (upd && kk == 3) ? nv : rv[3]; rf[3] = (upd && kk == 3) ? nf : rf[3];
            rv[4] = (upd && kk == 4) ? nv : rv[4]; rf[4] = (upd && kk == 4) ? nf : rf[4];
            rv[5] = (upd && kk == 5) ? nv : rv[5]; rf[5] = (upd && kk == 5) ? nf : rf[5];
            rv[6] = (upd && kk == 6) ? nv : rv[6]; rf[6] = (upd && kk == 6) ? nf : rf[6];
            rv[7] = (upd && kk == 7) ? nv : rv[7]; rf[7] = (upd && kk == 7) ? nf : rf[7];
            act2 = __ballot(dm2 != 0);
        }
    }
}

// ---------------- apply permutation (coords + feats + perm float, fused)
__global__ void scatter_all(const float* __restrict__ coords,
    const float* __restrict__ feats, const int* __restrict__ perm,
    float* __restrict__ dstCoords, float* __restrict__ dstFeats,
    float* __restrict__ permF)
{
    int tid = blockIdx.x * 256 + threadIdx.x;   // NB*NG*96 float4s
    int rc = tid / 96;
    int q = tid - rc * 96;
    int b = rc >> 9;
    int p = perm[rc];
    const float4* s4 = (const float4*)(feats + (size_t)rc * NC);
    float4* d4 = (float4*)(dstFeats + ((size_t)(b << 9) + p) * NC);
    d4[q] = s4[q];
    if (q == 0) {
        permF[rc] = (float)p;
        size_t so = (size_t)rc * 3;
        size_t dd = ((size_t)(b << 9) + p) * 3;
        dstCoords[dd] = coords[so];
        dstCoords[dd + 1] = coords[so + 1];
        dstCoords[dd + 2] = coords[so + 2];
    }
}

extern "C" void kernel_launch(void* const* d_in, const int* in_sizes, int n_in,
                              void* d_out, int out_size, void* d_ws, size_t ws_size,
                              hipStream_t stream)
{
    const float* coords = (const float*)d_in[0];
    const float* feats  = (const float*)d_in[1];
    const float* W1 = (const float*)d_in[2];
    const float* b1 = (const float*)d_in[3];
    const float* W2 = (const float*)d_in[4];
    const float* b2 = (const float*)d_in[5];

    float* out = (float*)d_out;
    float* outCoords = out;
    float* outFeats  = out + (size_t)NB * NG * 3;
    float* outPerm   = out + (size_t)NB * NG * 3 + (size_t)NB * NG * NC;

    float* ws = (float*)d_ws;
    float* h   = ws;                                  // 16384*768 (reused as P)
    float* A0  = h + (size_t)NB * NG * NH;            // 16384*512
    float* u   = A0 + (size_t)NB * NG * NG;           // 16384
    float* vA  = u + NB * NG;                         // 16384
    float* ps0 = vA + NB * NG;                        // 32*16*512
    float* ps1 = ps0 + NB * 16 * NG;                  // 32*16*512
    int* rbCr  = (int*)(ps1 + NB * 16 * NG);          // 16384
    int* rbCc  = rbCr + NB * NG;                      // 16384
    unsigned long long* freeRow = (unsigned long long*)(rbCc + NB * NG); // 256
    unsigned long long* freeCol = freeRow + NB * 8;   // 256
    int* remaining = (int*)(freeCol + NB * 8);        // 32
    int* permInt   = remaining + 32;                  // 16384
    float* vB  = (float*)(permInt + NB * NG);         // 16384
    bf16_t* pB1 = (bf16_t*)(vB + NB * NG);            // 12*3*768*32 bf16
    bf16_t* pB2 = pB1 + 12 * 3 * NH * 32;             // 24*3*512*32 bf16

    const int M = NB * NG;  // 16384

    // presplit weights into fragment-ordered bf16 planes (tiny, memory-bound)
    presplit_W<<<dim3((12 * NH + 255) / 256), 256, 0, stream>>>(W1, pB1, NC, NH);
    presplit_W<<<dim3((24 * NG + 255) / 256), 256, 0, stream>>>(W2, pB2, NH, NG);

    // h = relu(feats @ W1 + b1)
    gemm_bias_mfma<<<dim3((M / 64) * (NH / 128)), 256, 0, stream>>>(
        feats, pB1, b1, h, M, NH, NC, 0);
    // A0 = (h @ W2 + b2) / TAU
    gemm_bias_mfma<<<dim3((M / 64) * (NG / 128)), 256, 0, stream>>>(
        h, pB2, b2, A0, M, NG, NH, 1);

    hipMemsetAsync(vA, 0, (size_t)NB * NG * sizeof(float), stream);

    // fused Sinkhorn (16 blocks/batch, 8 waves, 2-deep prefetch): dbuf v/ps.
    float* pbuf[2] = { ps0, ps1 };
    for (int i = 1; i <= 10; ++i) {
        const float* vin = (i % 2 == 0) ? vA : vB;
        float* vout      = (i % 2 == 0) ? vB : vA;
        const float* pin = pbuf[i & 1];
        float* pout      = pbuf[(i - 1) & 1];
        sinkhorn_iter_fused<<<dim3(NB * 16), 512, 0, stream>>>(
            A0, u, vin, vout, pin, pout, (i == 1) ? 1 : 0);
    }
    col_combine_final<<<dim3(M / 256), 256, 0, stream>>>(pbuf[1], vB, vA);

    float* P = h;
    p_rowmax<<<dim3(M / 4), 256, 0, stream>>>(A0, u, vA, P, rbCr, rbCc,
                                              freeRow, freeCol, remaining);

    for (int r = 0; r < 6; ++r)
        mutual_round<<<dim3(NB), 512, 0, stream>>>(P, rbCr, rbCc, freeRow,
                                                   freeCol, remaining, permInt);

    greedy_cleanup<<<dim3(NB), 64, 0, stream>>>(P, freeRow, freeCol,
                                                remaining, permInt);

    scatter_all<<<dim3((NB * NG * 96) / 256), 256, 0, stream>>>(
        coords, feats, permInt, outCoords, outFeats, outPerm);
}

// Round 26
// 342.514 us; speedup vs baseline: 1.0448x; 1.0448x over previous
//
#include <hip/hip_runtime.h>
#include <math.h>

#define NB 32
#define NG 512
#define NC 384
#define NH 768

typedef float f32x4v __attribute__((ext_vector_type(4)));
typedef __bf16 bf16_t;
typedef bf16_t bf16x8 __attribute__((ext_vector_type(8)));
typedef bf16_t bf16x4 __attribute__((ext_vector_type(4)));

__device__ __forceinline__ void split3(float x, bf16_t& h, bf16_t& m, bf16_t& lo)
{
    h = (bf16_t)x;
    float r1 = x - (float)h;
    m = (bf16_t)r1;
    float r2 = r1 - (float)m;
    lo = (bf16_t)r2;
}

// ---------------- Presplit weights into fragment-ordered bf16 planes.
__global__ __launch_bounds__(256) void presplit_W(
    const float* __restrict__ W, bf16_t* __restrict__ planeB, int K, int N)
{
    int tid = blockIdx.x * 256 + threadIdx.x;
    int nkc = K >> 5;
    if (tid >= nkc * N) return;
    int kc = tid / N;
    int col = tid - kc * N;
    bf16x8 rh[4], rm[4], rl[4];
#pragma unroll
    for (int k = 0; k < 32; k++) {
        float x = W[(size_t)(kc * 32 + k) * N + col];
        bf16_t h, m, lo;
        split3(x, h, m, lo);
        const int s = (k >> 2) & 3;
        const int sub = ((k >> 4) << 2) + (k & 3);
        rh[s][sub] = h; rm[s][sub] = m; rl[s][sub] = lo;
    }
    int swz = (col >> 1) & 3;
    size_t b0 = ((size_t)(kc * 3 + 0) * N + col) * 32;
    size_t b1 = ((size_t)(kc * 3 + 1) * N + col) * 32;
    size_t b2 = ((size_t)(kc * 3 + 2) * N + col) * 32;
#pragma unroll
    for (int s = 0; s < 4; s++) {
        int d = (s ^ swz) << 3;
        *(bf16x8*)&planeB[b0 + d] = rh[s];
        *(bf16x8*)&planeB[b1 + d] = rm[s];
        *(bf16x8*)&planeB[b2 + d] = rl[s];
    }
}

// ---------------- GEMM via bf16 MFMA (round-20 structure + round-25 XCD
// swizzle: FETCH 80->34 MB, MfmaUtil 45%, ~74 us -- kept).
__global__ __launch_bounds__(256, 4) void gemm_bias_mfma(
    const float* __restrict__ A, const bf16_t* __restrict__ planeB,
    const float* __restrict__ bias, float* __restrict__ Co,
    int M, int N, int K, int mode)
{
    __shared__ __align__(16) bf16_t sA[3][64][32];
    int ntiles = N >> 7;
    int cpx = gridDim.x >> 3;
    int bid = blockIdx.x;
    int wg = (bid & 7) * cpx + (bid >> 3);    // XCD-contiguous tile chunks
    int bm = (wg / ntiles) << 6;
    int bn = (wg % ntiles) << 7;
    int t = threadIdx.x;
    int l = t & 63, w = t >> 6;
    int wr = (w >> 1) << 5;
    int wc = (w & 1) << 6;
    int fr = l & 15;
    int fq = l >> 4;

    int sa_row = t >> 2;
    int sa_k0 = (t & 3) << 3;
    int qA = (sa_k0 >> 2) & 3;
    int hsel = (sa_k0 & 16) ? 4 : 0;
    int aswz = (sa_row >> 1) & 3;
    int colQ0 = ((qA ^ aswz) << 3) + hsel;
    int colQ1 = (((qA + 1) ^ aswz) << 3) + hsel;
    const float* apBase = A + (size_t)(bm + sa_row) * K + sa_k0;

    size_t planeStride = (size_t)N << 5;
    int rb0 = wc + 0 * 16 + fr, rb1 = wc + 1 * 16 + fr;
    int rb2 = wc + 2 * 16 + fr, rb3 = wc + 3 * 16 + fr;
    size_t o0 = ((size_t)(bn + rb0) << 5) + ((fq ^ ((rb0 >> 1) & 3)) << 3);
    size_t o1 = ((size_t)(bn + rb1) << 5) + ((fq ^ ((rb1 >> 1) & 3)) << 3);
    size_t o2 = ((size_t)(bn + rb2) << 5) + ((fq ^ ((rb2 >> 1) & 3)) << 3);
    size_t o3 = ((size_t)(bn + rb3) << 5) + ((fq ^ ((rb3 >> 1) & 3)) << 3);

    f32x4v acc[2][4];
#pragma unroll
    for (int i = 0; i < 2; i++)
#pragma unroll
        for (int j = 0; j < 4; j++) acc[i][j] = (f32x4v)(0.f);

    float4 qa0 = *(const float4*)(apBase);
    float4 qa1 = *(const float4*)(apBase + 4);
    bf16x8 b0H = *(const bf16x8*)&planeB[o0];
    bf16x8 b0M = *(const bf16x8*)&planeB[planeStride + o0];
    bf16x8 b0L = *(const bf16x8*)&planeB[2 * planeStride + o0];
    bf16x8 b1H = *(const bf16x8*)&planeB[o1];
    bf16x8 b1M = *(const bf16x8*)&planeB[planeStride + o1];
    bf16x8 b1L = *(const bf16x8*)&planeB[2 * planeStride + o1];

    int nkc = K >> 5;
    for (int kc = 0; kc < K; kc += 32) {
        int kci = kc >> 5;
        int kciN = (kci + 1 < nkc) ? kci + 1 : kci;
        const bf16_t* pb  = planeB + (size_t)(kci * 3) * planeStride;
        const bf16_t* pbn = planeB + (size_t)(kciN * 3) * planeStride;
        __syncthreads();
        {
            float xs[8] = { qa0.x, qa0.y, qa0.z, qa0.w,
                            qa1.x, qa1.y, qa1.z, qa1.w };
            bf16_t hs[8], ms[8], ls[8];
#pragma unroll
            for (int e = 0; e < 8; e++) split3(xs[e], hs[e], ms[e], ls[e]);
            *(bf16x4*)&sA[0][sa_row][colQ0] = (bf16x4){ hs[0], hs[1], hs[2], hs[3] };
            *(bf16x4*)&sA[0][sa_row][colQ1] = (bf16x4){ hs[4], hs[5], hs[6], hs[7] };
            *(bf16x4*)&sA[1][sa_row][colQ0] = (bf16x4){ ms[0], ms[1], ms[2], ms[3] };
            *(bf16x4*)&sA[1][sa_row][colQ1] = (bf16x4){ ms[4], ms[5], ms[6], ms[7] };
            *(bf16x4*)&sA[2][sa_row][colQ0] = (bf16x4){ ls[0], ls[1], ls[2], ls[3] };
            *(bf16x4*)&sA[2][sa_row][colQ1] = (bf16x4){ ls[4], ls[5], ls[6], ls[7] };
        }
        __syncthreads();
        if (kc + 32 < K) {
            const float* ap = apBase + kc + 32;
            qa0 = *(const float4*)(ap);
            qa1 = *(const float4*)(ap + 4);
        }
        bf16x8 b2H = *(const bf16x8*)&pb[o2];
        bf16x8 b2M = *(const bf16x8*)&pb[planeStride + o2];
        bf16x8 b2L = *(const bf16x8*)&pb[2 * planeStride + o2];
        bf16x8 b3H = *(const bf16x8*)&pb[o3];
        bf16x8 b3M = *(const bf16x8*)&pb[planeStride + o3];
        bf16x8 b3L = *(const bf16x8*)&pb[2 * planeStride + o3];
        bf16x8 afH[2], afM[2], afL[2];
#pragma unroll
        for (int i = 0; i < 2; i++) {
            int ra = wr + i * 16 + fr;
            int pk = (fq ^ ((ra >> 1) & 3)) << 3;
            afH[i] = *(const bf16x8*)&sA[0][ra][pk];
            afM[i] = *(const bf16x8*)&sA[1][ra][pk];
            afL[i] = *(const bf16x8*)&sA[2][ra][pk];
        }
#define MFMA6(i, j, BH, BM, BL)                                               \
        acc[i][j] = __builtin_amdgcn_mfma_f32_16x16x32_bf16(                  \
            afH[i], BH, acc[i][j], 0, 0, 0);                                  \
        acc[i][j] = __builtin_amdgcn_mfma_f32_16x16x32_bf16(                  \
            afH[i], BM, acc[i][j], 0, 0, 0);                                  \
        acc[i][j] = __builtin_amdgcn_mfma_f32_16x16x32_bf16(                  \
            afM[i], BH, acc[i][j], 0, 0, 0);                                  \
        acc[i][j] = __builtin_amdgcn_mfma_f32_16x16x32_bf16(                  \
            afM[i], BM, acc[i][j], 0, 0, 0);                                  \
        acc[i][j] = __builtin_amdgcn_mfma_f32_16x16x32_bf16(                  \
            afH[i], BL, acc[i][j], 0, 0, 0);                                  \
        acc[i][j] = __builtin_amdgcn_mfma_f32_16x16x32_bf16(                  \
            afL[i], BH, acc[i][j], 0, 0, 0);
        MFMA6(0, 0, b0H, b0M, b0L)
        MFMA6(1, 0, b0H, b0M, b0L)
        MFMA6(0, 1, b1H, b1M, b1L)
        MFMA6(1, 1, b1H, b1M, b1L)
        b0H = *(const bf16x8*)&pbn[o0];
        b0M = *(const bf16x8*)&pbn[planeStride + o0];
        b0L = *(const bf16x8*)&pbn[2 * planeStride + o0];
        b1H = *(const bf16x8*)&pbn[o1];
        b1M = *(const bf16x8*)&pbn[planeStride + o1];
        b1L = *(const bf16x8*)&pbn[2 * planeStride + o1];
        MFMA6(0, 2, b2H, b2M, b2L)
        MFMA6(1, 2, b2H, b2M, b2L)
        MFMA6(0, 3, b3H, b3M, b3L)
        MFMA6(1, 3, b3H, b3M, b3L)
#undef MFMA6
    }

    int orow = fq << 2;
#pragma unroll
    for (int j = 0; j < 4; j++) {
        int colg = bn + wc + j * 16 + fr;
        float bj = bias[colg];
#pragma unroll
        for (int i = 0; i < 2; i++) {
            int rowg = bm + wr + i * 16 + orow;
#pragma unroll
            for (int r = 0; r < 4; r++) {
                float val = acc[i][j][r] + bj;
                val = (mode == 0) ? fmaxf(val, 0.f) : val / 0.1f;
                Co[(size_t)(rowg + r) * N + colg] = val;
            }
        }
    }
}

// ======== DPP reduce networks to lane 63 (pure VALU) ========
#define DPP6_MAXF(x)                                                              \
    { int _t;                                                                     \
      _t = __builtin_amdgcn_update_dpp(__float_as_int(x), __float_as_int(x),      \
               0x111, 0xf, 0xf, false); x = fmaxf(x, __int_as_float(_t));         \
      _t = __builtin_amdgcn_update_dpp(__float_as_int(x), __float_as_int(x),      \
               0x112, 0xf, 0xf, false); x = fmaxf(x, __int_as_float(_t));         \
      _t = __builtin_amdgcn_update_dpp(__float_as_int(x), __float_as_int(x),      \
               0x114, 0xf, 0xf, false); x = fmaxf(x, __int_as_float(_t));         \
      _t = __builtin_amdgcn_update_dpp(__float_as_int(x), __float_as_int(x),      \
               0x118, 0xf, 0xf, false); x = fmaxf(x, __int_as_float(_t));         \
      _t = __builtin_amdgcn_update_dpp(__float_as_int(x), __float_as_int(x),      \
               0x142, 0xa, 0xf, false); x = fmaxf(x, __int_as_float(_t));         \
      _t = __builtin_amdgcn_update_dpp(__float_as_int(x), __float_as_int(x),      \
               0x143, 0xc, 0xf, false); x = fmaxf(x, __int_as_float(_t)); }

#define DPP6_ADDF(x)                                                              \
    { int _t;                                                                     \
      _t = __builtin_amdgcn_update_dpp(__float_as_int(x), __float_as_int(x),      \
               0x111, 0xf, 0xf, false); x = x + __int_as_float(_t);               \
      _t = __builtin_amdgcn_update_dpp(__float_as_int(x), __float_as_int(x),      \
               0x112, 0xf, 0xf, false); x = x + __int_as_float(_t);               \
      _t = __builtin_amdgcn_update_dpp(__float_as_int(x), __float_as_int(x),      \
               0x114, 0xf, 0xf, false); x = x + __int_as_float(_t);               \
      _t = __builtin_amdgcn_update_dpp(__float_as_int(x), __float_as_int(x),      \
               0x118, 0xf, 0xf, false); x = x + __int_as_float(_t);               \
      _t = __builtin_amdgcn_update_dpp(__float_as_int(x), __float_as_int(x),      \
               0x142, 0xa, 0xf, false); x = x + __int_as_float(_t);               \
      _t = __builtin_amdgcn_update_dpp(__float_as_int(x), __float_as_int(x),      \
               0x143, 0xc, 0xf, false); x = x + __int_as_float(_t); }

// ---------------- Fused Sinkhorn iteration (round-24 structure: NB*8 grid,
// 512 thr / 8 waves, 8 rows/wave, 2-deep prefetch -- round-25's 16-block
// split doubled ps traffic and regressed; reverted).
__global__ __launch_bounds__(512) void sinkhorn_iter_fused(
    const float* __restrict__ A0, float* __restrict__ uu,
    const float* __restrict__ vIn, float* __restrict__ vOut,
    const float* __restrict__ psIn, float* __restrict__ psOut, int first)
{
    int blk = blockIdx.x;          // NB*8
    int b = blk >> 3, rc = blk & 7;
    int t = threadIdx.x;           // 0..511
    int l = t & 63, w = t >> 6;    // 8 waves
    __shared__ __align__(16) float svv[512];

    if (first) {
        svv[t] = 0.f;
    } else {
        float S = 0.f;
#pragma unroll
        for (int r8 = 0; r8 < 8; r8++) S += psIn[((b << 3) + r8) * NG + t];
        float nv = vIn[(b << 9) + t] - __logf(S);
        svv[t] = nv;
        if (rc == 0) vOut[(b << 9) + t] = nv;
    }
    __syncthreads();

    float4 v0 = *(const float4*)(&svv[4 * l]);
    float4 v1 = *(const float4*)(&svv[256 + 4 * l]);
    int row0 = (rc << 6) + (w << 3);        // 8 rows per wave
    const float* base = A0 + ((size_t)((b << 9) + row0) << 9);

    float cs0 = 0.f, cs1 = 0.f, cs2 = 0.f, cs3 = 0.f;
    float cs4 = 0.f, cs5 = 0.f, cs6 = 0.f, cs7 = 0.f;

    float4 a0 = *(const float4*)(base + 4 * l);
    float4 a1 = *(const float4*)(base + 256 + 4 * l);
    float4 b0 = *(const float4*)(base + (1 << 9) + 4 * l);
    float4 b1 = *(const float4*)(base + (1 << 9) + 256 + 4 * l);

#pragma unroll
    for (int rr = 0; rr < 8; ++rr) {
        float4 c0, c1;
        if (rr < 6) {
            const float* nrow = base + ((size_t)(rr + 2) << 9);
            c0 = *(const float4*)(nrow + 4 * l);
            c1 = *(const float4*)(nrow + 256 + 4 * l);
        }
        float x0 = a0.x + v0.x, x1 = a0.y + v0.y;
        float x2 = a0.z + v0.z, x3 = a0.w + v0.w;
        float x4 = a1.x + v1.x, x5 = a1.y + v1.y;
        float x6 = a1.z + v1.z, x7 = a1.w + v1.w;
        float m = fmaxf(fmaxf(fmaxf(x0, x1), fmaxf(x2, x3)),
                        fmaxf(fmaxf(x4, x5), fmaxf(x6, x7)));
        DPP6_MAXF(m)
        int mi = __builtin_amdgcn_readlane(__float_as_int(m), 63);
        m = __int_as_float(mi);
        float e0 = __expf(x0 - m), e1 = __expf(x1 - m);
        float e2 = __expf(x2 - m), e3 = __expf(x3 - m);
        float e4 = __expf(x4 - m), e5 = __expf(x5 - m);
        float e6 = __expf(x6 - m), e7 = __expf(x7 - m);
        float s = ((e0 + e1) + (e2 + e3)) + ((e4 + e5) + (e6 + e7));
        DPP6_ADDF(s)
        int si = __builtin_amdgcn_readlane(__float_as_int(s), 63);
        s = __int_as_float(si);
        float inv = 1.0f / s;
        cs0 += e0 * inv; cs1 += e1 * inv; cs2 += e2 * inv; cs3 += e3 * inv;
        cs4 += e4 * inv; cs5 += e5 * inv; cs6 += e6 * inv; cs7 += e7 * inv;
        if (l == 63) uu[(b << 9) + row0 + rr] = -(m + __logf(s));
        a0 = b0; a1 = b1;
        b0 = c0; b1 = c1;
    }

    __shared__ float sacc[8][512];
    float4 w0; w0.x = cs0; w0.y = cs1; w0.z = cs2; w0.w = cs3;
    float4 w1; w1.x = cs4; w1.y = cs5; w1.z = cs6; w1.w = cs7;
    *(float4*)&sacc[w][4 * l] = w0;
    *(float4*)&sacc[w][256 + 4 * l] = w1;
    __syncthreads();
    float pA = sacc[0][t] + sacc[1][t] + sacc[2][t] + sacc[3][t]
             + sacc[4][t] + sacc[5][t] + sacc[6][t] + sacc[7][t];
    int o = ((b << 3) + rc) * NG;
    psOut[o + t] = pA;
}

// ---------------- final combine: vOut = vIn - log(colsum(psIn))
__global__ __launch_bounds__(256) void col_combine_final(
    const float* __restrict__ psIn, const float* __restrict__ vIn,
    float* __restrict__ vOut)
{
    int tid = blockIdx.x * 256 + threadIdx.x;  // NB*NG
    int b = tid >> 9, j = tid & 511;
    float S = 0.f;
#pragma unroll
    for (int r8 = 0; r8 < 8; r8++) S += psIn[((b << 3) + r8) * NG + j];
    vOut[tid] = vIn[tid] - __logf(S);
}

// wave-cooperative masked row argmax over cols 8l..8l+7 per lane.
__device__ __forceinline__ void masked_row_argmax(
    const float* __restrict__ rowp, int l, unsigned int free8, int rr,
    float& outV, int& outF)
{
    float4 x0 = *(const float4*)(rowp + 8 * l);
    float4 x1 = *(const float4*)(rowp + 8 * l + 4);
    float q0 = (free8 & 1u)   ? x0.x : -1.0f;
    float q1 = (free8 & 2u)   ? x0.y : -1.0f;
    float q2 = (free8 & 4u)   ? x0.z : -1.0f;
    float q3 = (free8 & 8u)   ? x0.w : -1.0f;
    float q4 = (free8 & 16u)  ? x1.x : -1.0f;
    float q5 = (free8 & 32u)  ? x1.y : -1.0f;
    float q6 = (free8 & 64u)  ? x1.z : -1.0f;
    float q7 = (free8 & 128u) ? x1.w : -1.0f;
    float lm = fmaxf(fmaxf(fmaxf(q0, q1), fmaxf(q2, q3)),
                     fmaxf(fmaxf(q4, q5), fmaxf(q6, q7)));
    int sb = (rr << 9) + 8 * l;
    int lf = 0x7FFFFFFF;
    lf = (q7 == lm) ? sb + 7 : lf;
    lf = (q6 == lm) ? sb + 6 : lf;
    lf = (q5 == lm) ? sb + 5 : lf;
    lf = (q4 == lm) ? sb + 4 : lf;
    lf = (q3 == lm) ? sb + 3 : lf;
    lf = (q2 == lm) ? sb + 2 : lf;
    lf = (q1 == lm) ? sb + 1 : lf;
    lf = (q0 == lm) ? sb + 0 : lf;
    float gg = lm;
    DPP6_MAXF(gg)
    int ggi = __builtin_amdgcn_readlane(__float_as_int(gg), 63);
    float g1 = __int_as_float(ggi);
    unsigned long long tb = __ballot(lm == g1);
    int tl = __ffsll(tb) - 1;
    outV = g1;
    outF = __builtin_amdgcn_readlane(lf, tl);
}

// ---------------- P = exp((A0+u)+v) (libm expf) + per-row argmax + state init.
__global__ __launch_bounds__(256) void p_rowmax(
    const float* __restrict__ A0, const float* __restrict__ uu,
    const float* __restrict__ vv, float* __restrict__ P,
    int* __restrict__ rbCr, int* __restrict__ rbCc,
    unsigned long long* __restrict__ freeRow,
    unsigned long long* __restrict__ freeCol,
    int* __restrict__ remaining)
{
    if (blockIdx.x == 0) {
        int t = threadIdx.x;
        freeRow[t] = ~0ULL;
        freeCol[t] = ~0ULL;
        if (t < NB) remaining[t] = NG;
    }
    int wrow = blockIdx.x * 4 + (threadIdx.x >> 6);
    int l = threadIdx.x & 63;
    int b = wrow >> 9;
    float ur = uu[wrow];
    const float* vb = vv + (b << 9);
    size_t ro = (size_t)wrow << 9;
    float4 a0 = *(const float4*)(A0 + ro + 8 * l);
    float4 a1 = *(const float4*)(A0 + ro + 8 * l + 4);
    float4 v0 = *(const float4*)(vb + 8 * l);
    float4 v1 = *(const float4*)(vb + 8 * l + 4);
    float p0 = expf(a0.x + ur + v0.x);
    float p1 = expf(a0.y + ur + v0.y);
    float p2 = expf(a0.z + ur + v0.z);
    float p3 = expf(a0.w + ur + v0.w);
    float p4 = expf(a1.x + ur + v1.x);
    float p5 = expf(a1.y + ur + v1.y);
    float p6 = expf(a1.z + ur + v1.z);
    float p7 = expf(a1.w + ur + v1.w);
    float4 o0; o0.x = p0; o0.y = p1; o0.z = p2; o0.w = p3;
    float4 o1; o1.x = p4; o1.y = p5; o1.z = p6; o1.w = p7;
    *(float4*)(P + ro + 8 * l) = o0;
    *(float4*)(P + ro + 8 * l + 4) = o1;
    float mv = fmaxf(fmaxf(fmaxf(p0, p1), fmaxf(p2, p3)),
                     fmaxf(fmaxf(p4, p5), fmaxf(p6, p7)));
    int cb = 8 * l;
    int f = 0x7FFFFFFF;
    f = (p7 == mv) ? cb + 7 : f;
    f = (p6 == mv) ? cb + 6 : f;
    f = (p5 == mv) ? cb + 5 : f;
    f = (p4 == mv) ? cb + 4 : f;
    f = (p3 == mv) ? cb + 3 : f;
    f = (p2 == mv) ? cb + 2 : f;
    f = (p1 == mv) ? cb + 1 : f;
    f = (p0 == mv) ? cb + 0 : f;
    float g = mv;
    DPP6_MAXF(g)
    int gi = __builtin_amdgcn_readlane(__float_as_int(g), 63);
    float gm = __int_as_float(gi);
    unsigned long long tb = __ballot(mv == gm);
    int tl = __ffsll(tb) - 1;
    int bestc = __builtin_amdgcn_readlane(f, tl);
    if (l == 0) { rbCr[wrow] = bestc; rbCc[wrow] = -1; }
}

// ---------------- One parallel mutual-max round (exact greedy equivalence).
__global__ __launch_bounds__(512) void mutual_round(
    const float* __restrict__ P, int* __restrict__ rbCr, int* __restrict__ rbCc,
    unsigned long long* __restrict__ freeRow,
    unsigned long long* __restrict__ freeCol,
    int* __restrict__ remaining, int* __restrict__ permInt)
{
    int b = blockIdx.x;
    if (remaining[b] == 0) return;
    int t = threadIdx.x;
    int l = t & 63;
    int w = t >> 6;
    const float* Pb = P + (size_t)b * NG * NG;

    __shared__ unsigned int fr[16], fc[16];
    __shared__ int sRC[NG];
    __shared__ int sCC[NG];
    __shared__ int freeList[NG];
    __shared__ int dirtyRows[NG];
    __shared__ int nFree, nDirtyRow, takeCnt;
    __shared__ int wCnt[8], wOff[8];

    if (t < 8) {
        unsigned long long x = freeRow[b * 8 + t];
        fr[2 * t] = (unsigned)x; fr[2 * t + 1] = (unsigned)(x >> 32);
    } else if (t < 16) {
        int i = t - 8;
        unsigned long long x = freeCol[b * 8 + i];
        fc[2 * i] = (unsigned)x; fc[2 * i + 1] = (unsigned)(x >> 32);
    }
    sRC[t] = rbCr[(b << 9) + t];
    sCC[t] = rbCc[(b << 9) + t];
    if (t == 0) { nDirtyRow = 0; takeCnt = 0; }
    __syncthreads();

    bool isFree = (fr[t >> 5] >> (t & 31)) & 1u;
    unsigned long long bm = __ballot(isFree);
    if (l == 0) wCnt[w] = __popcll(bm);
    if (isFree) {
        int c = sRC[t];
        if (!((fc[c >> 5] >> (c & 31)) & 1u)) {
            int d = atomicAdd(&nDirtyRow, 1);
            dirtyRows[d] = t;
        }
    }
    __syncthreads();
    if (t == 0) {
        int s = 0;
#pragma unroll
        for (int i = 0; i < 8; i++) { wOff[i] = s; s += wCnt[i]; }
        nFree = s;
    }
    __syncthreads();
    if (isFree) {
        int rank = __popcll(bm & ((1ULL << l) - 1ULL));
        freeList[wOff[w] + rank] = t;
    }
    __syncthreads();

    int nd = nDirtyRow;
    for (int d = w; d < nd; d += 8) {
        int r = dirtyRows[d];
        unsigned int free8 = (fc[l >> 2] >> ((l & 3) * 8)) & 0xFFu;
        float nv; int nf;
        masked_row_argmax(Pb + ((size_t)r << 9), l, free8, r, nv, nf);
        if (l == 0) {
            int c = nf & 511;
            sRC[r] = c;
            rbCr[(b << 9) + r] = c;
        }
    }
    __syncthreads();

    bool colFree = (fc[t >> 5] >> (t & 31)) & 1u;
    int cachedR = sCC[t];
    bool colDirty = colFree &&
        (cachedR < 0 || !((fr[cachedR >> 5] >> (cachedR & 31)) & 1u));
    if (colDirty) {
        float best = -1.f; int bestr = 0x7FFFFFFF;
        int nf2 = nFree;
        int i = 0;
        for (; i + 4 <= nf2; i += 4) {
            int r0 = freeList[i], r1 = freeList[i + 1];
            int r2 = freeList[i + 2], r3 = freeList[i + 3];
            float v0 = Pb[((size_t)r0 << 9) + t];
            float v1 = Pb[((size_t)r1 << 9) + t];
            float v2 = Pb[((size_t)r2 << 9) + t];
            float v3 = Pb[((size_t)r3 << 9) + t];
            if (v0 > best) { best = v0; bestr = r0; }
            if (v1 > best) { best = v1; bestr = r1; }
            if (v2 > best) { best = v2; bestr = r2; }
            if (v3 > best) { best = v3; bestr = r3; }
        }
        for (; i < nf2; ++i) {
            int ri = freeList[i];
            float vv2 = Pb[((size_t)ri << 9) + t];
            if (vv2 > best) { best = vv2; bestr = ri; }
        }
        sCC[t] = bestr;
        rbCc[(b << 9) + t] = bestr;
    }
    __syncthreads();

    if (colFree) {
        int r = sCC[t];
        if (r >= 0 && r < NG && sRC[r] == t) {
            permInt[(b << 9) + r] = t;
            atomicAnd(&fr[r >> 5], ~(1u << (r & 31)));
            atomicAnd(&fc[t >> 5], ~(1u << (t & 31)));
            atomicAdd(&takeCnt, 1);
        }
    }
    __syncthreads();
    if (t < 8) {
        freeRow[b * 8 + t] =
            ((unsigned long long)fr[2 * t + 1] << 32) | fr[2 * t];
    } else if (t < 16) {
        int i = t - 8;
        freeCol[b * 8 + i] =
            ((unsigned long long)fc[2 * i + 1] << 32) | fc[2 * i];
    }
    if (t == 0) remaining[b] = remaining[b] - takeCnt;
}

// ---------------- Exact sequential cleanup (rarely does work).
__global__ __launch_bounds__(64) void greedy_cleanup(
    const float* __restrict__ P,
    const unsigned long long* __restrict__ freeRow,
    const unsigned long long* __restrict__ freeCol,
    const int* __restrict__ remaining, int* __restrict__ permInt)
{
    int b = blockIdx.x;
    if (remaining[b] == 0) return;
    int l = threadIdx.x;
    const float* Pb = P + (size_t)b * NG * NG;

    unsigned long long wR = freeRow[b * 8 + (l >> 3)];
    unsigned int myRows = (unsigned int)((wR >> ((l & 7) * 8)) & 0xFF);
    unsigned long long wC = freeCol[b * 8 + (l >> 3)];
    unsigned int free8 = (unsigned int)((wC >> ((l & 7) * 8)) & 0xFF);

    float rv[8]; int rf[8];
#pragma unroll
    for (int k = 0; k < 8; k++) { rv[k] = -1.f; rf[k] = 0x7FFFFFFF; }

    int dmk = (int)myRows;
    unsigned long long act = __ballot(dmk != 0);
    while (act) {
        int src = __ffsll(act) - 1;
        int kk = __ffs(__builtin_amdgcn_readlane(dmk, src)) - 1;
        if (l == src) dmk &= ~(1 << kk);
        int rr = (src << 3) + kk;
        float nv; int nf;
        masked_row_argmax(Pb + ((size_t)rr << 9), l, free8, rr, nv, nf);
        bool upd = (l == src);
        rv[0] = (upd && kk == 0) ? nv : rv[0]; rf[0] = (upd && kk == 0) ? nf : rf[0];
        rv[1] = (upd && kk == 1) ? nv : rv[1]; rf[1] = (upd && kk == 1) ? nf : rf[1];
        rv[2] = (upd && kk == 2) ? nv : rv[2]; rf[2] = (upd && kk == 2) ? nf : rf[2];
        rv[3] = (upd && kk == 3) ? nv : rv[3]; rf[3] = (upd && kk == 3) ? nf : rf[3];
        rv[4] = (upd && kk == 4) ? nv : rv[4]; rf[4] = (upd && kk == 4) ? nf : rf[4];
        rv[5] = (upd && kk == 5) ? nv : rv[5]; rf[5] = (upd && kk == 5) ? nf : rf[5];
        rv[6] = (upd && kk == 6) ? nv : rv[6]; rf[6] = (upd && kk == 6) ? nf : rf[6];
        rv[7] = (upd && kk == 7) ? nv : rv[7]; rf[7] = (upd && kk == 7) ? nf : rf[7];
        act = __ballot(dmk != 0);
    }

    for (int step = 0; step < NG; ++step) {
        float mv = fmaxf(fmaxf(fmaxf(rv[0], rv[1]), fmaxf(rv[2], rv[3])),
                         fmaxf(fmaxf(rv[4], rv[5]), fmaxf(rv[6], rv[7])));
        int f = 0x7FFFFFFF;
        f = (rv[7] == mv) ? rf[7] : f;
        f = (rv[6] == mv) ? rf[6] : f;
        f = (rv[5] == mv) ? rf[5] : f;
        f = (rv[4] == mv) ? rf[4] : f;
        f = (rv[3] == mv) ? rf[3] : f;
        f = (rv[2] == mv) ? rf[2] : f;
        f = (rv[1] == mv) ? rf[1] : f;
        f = (rv[0] == mv) ? rf[0] : f;
        float g = mv;
        DPP6_MAXF(g)
        int gi = __builtin_amdgcn_readlane(__float_as_int(g), 63);
        float gm = __int_as_float(gi);
        if (gm < 0.f) break;
        unsigned long long tb = __ballot(mv == gm);
        int tl = __ffsll(tb) - 1;
        int bestf = __builtin_amdgcn_readlane(f, tl);
        int r = bestf >> 9, c = bestf & 511;
        if (l == 0) permInt[(b << 9) + r] = c;
        if (l == (c >> 3)) free8 &= ~(1u << (c & 7));
        int rl = r - (l << 3);
        int dm2 = 0;
#pragma unroll
        for (int k = 0; k < 8; k++) {
            bool alive = rv[k] >= 0.f;
            bool cm = ((rf[k] ^ c) & 511) == 0;
            bool taken = (rl == k);
            if (taken) rv[k] = -1.f;
            dm2 |= (alive && cm && !taken) ? (1 << k) : 0;
        }
        unsigned long long act2 = __ballot(dm2 != 0);
        while (act2) {
            int src = __ffsll(act2) - 1;
            int kk = __ffs(__builtin_amdgcn_readlane(dm2, src)) - 1;
            if (l == src) dm2 &= ~(1 << kk);
            int rr = (src << 3) + kk;
            float nv; int nf;
            masked_row_argmax(Pb + ((size_t)rr << 9), l, free8, rr, nv, nf);
            bool upd = (l == src);
            rv[0] = (upd && kk == 0) ? nv : rv[0]; rf[0] = (upd && kk == 0) ? nf : rf[0];
            rv[1] = (upd && kk == 1) ? nv : rv[1]; rf[1] = (upd && kk == 1) ? nf : rf[1];
            rv[2] = (upd && kk == 2) ? nv : rv[2]; rf[2] = (upd && kk == 2) ? nf : rf[2];
            rv[3] = (upd && kk == 3) ? nv : rv[3]; rf[3] = (upd && kk == 3) ? nf : rf[3];
            rv[4] = (upd && kk == 4) ? nv : rv[4]; rf[4] = (upd && kk == 4) ? nf : rf[4];
            rv[5] = (upd && kk == 5) ? nv : rv[5]; rf[5] = (upd && kk == 5) ? nf : rf[5];
            rv[6] = (upd && kk == 6) ? nv : rv[6]; rf[6] = (upd && kk == 6) ? nf : rf[6];
            rv[7] = (upd && kk == 7) ? nv : rv[7]; rf[7] = (upd && kk == 7) ? nf : rf[7];
            act2 = __ballot(dm2 != 0);
        }
    }
}

// ---------------- apply permutation (coords + feats + perm float, fused)
__global__ void scatter_all(const float* __restrict__ coords,
    const float* __restrict__ feats, const int* __restrict__ perm,
    float* __restrict__ dstCoords, float* __restrict__ dstFeats,
    float* __restrict__ permF)
{
    int tid = blockIdx.x * 256 + threadIdx.x;   // NB*NG*96 float4s
    int rc = tid / 96;
    int q = tid - rc * 96;
    int b = rc >> 9;
    int p = perm[rc];
    const float4* s4 = (const float4*)(feats + (size_t)rc * NC);
    float4* d4 = (float4*)(dstFeats + ((size_t)(b << 9) + p) * NC);
    d4[q] = s4[q];
    if (q == 0) {
        permF[rc] = (float)p;
        size_t so = (size_t)rc * 3;
        size_t dd = ((size_t)(b << 9) + p) * 3;
        dstCoords[dd] = coords[so];
        dstCoords[dd + 1] = coords[so + 1];
        dstCoords[dd + 2] = coords[so + 2];
    }
}

extern "C" void kernel_launch(void* const* d_in, const int* in_sizes, int n_in,
                              void* d_out, int out_size, void* d_ws, size_t ws_size,
                              hipStream_t stream)
{
    const float* coords = (const float*)d_in[0];
    const float* feats  = (const float*)d_in[1];
    const float* W1 = (const float*)d_in[2];
    const float* b1 = (const float*)d_in[3];
    const float* W2 = (const float*)d_in[4];
    const float* b2 = (const float*)d_in[5];

    float* out = (float*)d_out;
    float* outCoords = out;
    float* outFeats  = out + (size_t)NB * NG * 3;
    float* outPerm   = out + (size_t)NB * NG * 3 + (size_t)NB * NG * NC;

    float* ws = (float*)d_ws;
    float* h   = ws;                                  // 16384*768 (reused as P)
    float* A0  = h + (size_t)NB * NG * NH;            // 16384*512
    float* u   = A0 + (size_t)NB * NG * NG;           // 16384
    float* vA  = u + NB * NG;                         // 16384
    float* ps0 = vA + NB * NG;                        // 32*8*512
    float* ps1 = ps0 + NB * 8 * NG;                   // 32*8*512
    int* rbCr  = (int*)(ps1 + NB * 8 * NG);           // 16384
    int* rbCc  = rbCr + NB * NG;                      // 16384
    unsigned long long* freeRow = (unsigned long long*)(rbCc + NB * NG); // 256
    unsigned long long* freeCol = freeRow + NB * 8;   // 256
    int* remaining = (int*)(freeCol + NB * 8);        // 32
    int* permInt   = remaining + 32;                  // 16384
    float* vB  = (float*)(permInt + NB * NG);         // 16384
    bf16_t* pB1 = (bf16_t*)(vB + NB * NG);            // 12*3*768*32 bf16
    bf16_t* pB2 = pB1 + 12 * 3 * NH * 32;             // 24*3*512*32 bf16

    const int M = NB * NG;  // 16384

    // presplit weights into fragment-ordered bf16 planes (tiny, memory-bound)
    presplit_W<<<dim3((12 * NH + 255) / 256), 256, 0, stream>>>(W1, pB1, NC, NH);
    presplit_W<<<dim3((24 * NG + 255) / 256), 256, 0, stream>>>(W2, pB2, NH, NG);

    // h = relu(feats @ W1 + b1)
    gemm_bias_mfma<<<dim3((M / 64) * (NH / 128)), 256, 0, stream>>>(
        feats, pB1, b1, h, M, NH, NC, 0);
    // A0 = (h @ W2 + b2) / TAU
    gemm_bias_mfma<<<dim3((M / 64) * (NG / 128)), 256, 0, stream>>>(
        h, pB2, b2, A0, M, NG, NH, 1);

    hipMemsetAsync(vA, 0, (size_t)NB * NG * sizeof(float), stream);

    // fused Sinkhorn (round-24: 8 blocks/batch, 8 waves, 2-deep prefetch)
    float* pbuf[2] = { ps0, ps1 };
    for (int i = 1; i <= 10; ++i) {
        const float* vin = (i % 2 == 0) ? vA : vB;
        float* vout      = (i % 2 == 0) ? vB : vA;
        const float* pin = pbuf[i & 1];
        float* pout      = pbuf[(i - 1) & 1];
        sinkhorn_iter_fused<<<dim3(NB * 8), 512, 0, stream>>>(
            A0, u, vin, vout, pin, pout, (i == 1) ? 1 : 0);
    }
    col_combine_final<<<dim3(M / 256), 256, 0, stream>>>(pbuf[1], vB, vA);

    float* P = h;
    p_rowmax<<<dim3(M / 4), 256, 0, stream>>>(A0, u, vA, P, rbCr, rbCc,
                                              freeRow, freeCol, remaining);

    for (int r = 0; r < 6; ++r)
        mutual_round<<<dim3(NB), 512, 0, stream>>>(P, rbCr, rbCc, freeRow,
                                                   freeCol, remaining, permInt);

    greedy_cleanup<<<dim3(NB), 64, 0, stream>>>(P, freeRow, freeCol,
                                                remaining, permInt);

    scatter_all<<<dim3((NB * NG * 96) / 256), 256, 0, stream>>>(
        coords, feats, permInt, outCoords, outFeats, outPerm);
}